// Round 4
// baseline (306.563 us; speedup 1.0000x reference)
//
#include <hip/hip_runtime.h>
#include <math.h>

typedef __attribute__((ext_vector_type(8))) short bf16x8;   // 8 bf16 = 4 VGPRs
typedef __attribute__((ext_vector_type(4))) float floatx4;

static __device__ __forceinline__ short f2bf(float f) {
    union { float f; unsigned u; } a; a.f = f;
    unsigned r = a.u + 0x7fffu + ((a.u >> 16) & 1u);   // RNE
    return (short)(r >> 16);
}
static __device__ __forceinline__ float bf2f(short s) {
    union { unsigned u; float f; } c; c.u = ((unsigned)(unsigned short)s) << 16;
    return c.f;
}

// ---------------------------------------------------------------------------
// prep: 16 blocks; block bb:
//   - computes qwk rows [bb*16, bb*16+16) and packs them straight into Bq
//   - packs Wv / Wo rows [bb*16, bb*16+16) into Wvh / Bo (coalesced reads)
// Wvh layout note: Wvh is the FULL b-frag pack of Wv over nt = n>>4 —
// used as such by the fused PV phase.
// ---------------------------------------------------------------------------
__global__ __launch_bounds__(256) void prep_kernel(
    const float* __restrict__ query,        // [2][256]
    const float* __restrict__ Wk,           // [256][256]
    const float* __restrict__ rpe_bias,     // [9][16]
    const float* __restrict__ attn_scale_w, // [9][16]
    const float* __restrict__ Wv,           // [256][256]
    const float* __restrict__ Wo,           // [256][256]
    float* __restrict__ rpe_exp,            // out [9][16]
    float* __restrict__ rpe_scale,          // out [9][16]
    short* __restrict__ Bq,                 // out [4096]  (MFMA b-frag layout)
    short* __restrict__ Wvh,                // out [65536] (full b-frag pack)
    short* __restrict__ Bo)                 // out [65536]
{
    __shared__ float qn[16 * 33];
    __shared__ float Wt[16][260];
    __shared__ float qwk_s[16][17];
    int tid = threadIdx.x, bb = blockIdx.x;

    for (int i = tid; i < 512; i += 256) {
        int qq  = i >> 8;
        int rem = i & 255;
        int h   = rem >> 5;
        int d   = rem & 31;
        qn[((qq << 3) + h) * 33 + d] = query[i];
    }
    for (int i = tid; i < 16 * 256; i += 256)
        Wt[i >> 8][i & 255] = Wk[bb * 16 * 256 + i];
    __syncthreads();
    if (tid < 16) {
        float s = 0.f;
        #pragma unroll
        for (int d = 0; d < 32; ++d) { float t = qn[tid * 33 + d]; s += t * t; }
        float inv = 1.0f / ((sqrtf(s) + 1e-6f) * sqrtf(32.0f));
        #pragma unroll
        for (int d = 0; d < 32; ++d) qn[tid * 33 + d] *= inv;
    }
    __syncthreads();

    int g  = tid & 15;
    int Dl = tid >> 4;
    int h2 = g & 7;
    float acc = 0.f;
    #pragma unroll
    for (int d = 0; d < 32; ++d)
        acc += qn[g * 33 + d] * Wt[Dl][h2 * 32 + d];
    qwk_s[Dl][g] = acc;
    __syncthreads();

    // Bq pack for this block's 16 k-rows (b-frag: id = kc*512 + lane*8 + j)
    {
        int kl = tid >> 4, gg = tid & 15;
        int k  = bb * 16 + kl;
        int kc = k >> 5, q5 = k & 31, qd = q5 >> 3, j = q5 & 7;
        int lane = qd * 16 + gg;
        Bq[kc * 512 + lane * 8 + j] = f2bf(qwk_s[kl][gg]);
    }

    // Wvh / Bo pack: coalesced row reads (thread = column n)
    for (int kl = 0; kl < 16; ++kl) {
        int k  = bb * 16 + kl;
        int kc = k >> 5, q5 = k & 31, qd = q5 >> 3, j = q5 & 7;
        int n  = tid;
        int gg = n & 15;
        int lane = qd * 16 + gg;
        float vv = Wv[k * 256 + n];
        float vo = Wo[k * 256 + n];
        int nt  = n >> 4;
        Wvh[nt * 4096 + kc * 512 + lane * 8 + j] = f2bf(vv);
        Bo[nt * 4096 + kc * 512 + lane * 8 + j]  = f2bf(vo);
    }

    if (bb == 0 && tid < 144) {
        float r = expf(rpe_bias[tid]);
        rpe_exp[tid]   = r;
        rpe_scale[tid] = r * attn_scale_w[tid];
    }
}

// ---------------------------------------------------------------------------
// fused mega-kernel: block = 16 output pixels (half an output row), 512 thr.
// V-formulation (matches reference order): project V = X.Wv per INPUT pixel
// via MFMA, then the 9-point softmax-weighted stencil runs on V directly —
// the per-head channel copies of the old z-form collapse (8x less VALU).
// P0:  stage x window (112 rows x 256 ch) -> bf16 LDS (Xw)
// P1V: per wave (= m-tile, wv<7): preload 8 A-frags (own 16 Xw rows) into
//      regs; cost MFMA -> ces; then V = X.Wv (16 nt x 8 kc = 128 MFMA),
//      written IN PLACE over Xw (safe: A-frags preloaded, rows wave-owned).
// P2a/P2b: invden; wcoefs[h][w][op]
// P3:  stencil: pre[op][n] = sum_w wc[op][w][n>>5] * V[row(op,w)][n]
//      (72 FMA/thread) -> out_tr bf16 (pool, ces dead)
// P5:  out = out_tr . Wo
// ---------------------------------------------------------------------------
#define XROW 264
#define CESROW 19
__global__ __launch_bounds__(512) void fused_kernel(
    const float* __restrict__ x,          // [131072][256] fp32
    const float* __restrict__ rpe_exp,    // [9][16]
    const float* __restrict__ rpe_scale,  // [9][16]
    const short* __restrict__ Bq,         // [4096]
    const short* __restrict__ Wvh,        // [65536]
    const short* __restrict__ Bo,         // [65536]
    float* __restrict__ out)              // [32768][256] fp32
{
    __shared__ short Xw[112 * XROW];                        // 59136 B (X, then V)
    __shared__ __align__(16) unsigned char pool[112 * CESROW * 4]; // 8512 B
    __shared__ float wcoefs[8][9][16];                      // 4608 B [h][w][op]
    __shared__ float invden[16][16];                        // 1024 B (tot 73280)

    float* ces    = (float*)pool;     // live P1..P2b
    short* out_tr = (short*)pool;     // live P3..P5 (16 rows x XROW)

    int tid  = threadIdx.x;
    int lane = tid & 63, wv = tid >> 6;
    int m16  = lane & 15, quad = lane >> 4;

    int blk0 = blockIdx.x;
    int blk  = ((blk0 & 7) << 8) | (blk0 >> 3);  // XCD-contiguous, bijective
    int b   = blk >> 6;
    int io  = (blk >> 1) & 31;
    int hf  = blk & 1;
    int i0  = io * 2 - 1;
    int jbase = hf * 32 - 1;

    // ---- P0: stage window, coalesced, zero-fill OOB/pad ----
    #pragma unroll
    for (int i = 0; i < 7; ++i) {
        int it  = tid + i * 512;          // 0..3583 = 112 rows x 32 chunks
        int row = it >> 5;
        int l   = it & 31;
        int ky  = row / 34;
        int jloc = row - ky * 34;
        int ii = i0 + ky, jj = jbase + jloc;
        bool valid = (ky < 3) && (jloc < 33) &&
                     ((unsigned)ii < 64u) && ((unsigned)jj < 64u);
        bf16x8 s;
        if (valid) {
            const float* xp = x + ((size_t)(((b << 6) + ii) << 6) + jj) * 256 + l * 8;
            float4 f0 = *(const float4*)xp;
            float4 f1 = *(const float4*)(xp + 4);
            s[0] = f2bf(f0.x); s[1] = f2bf(f0.y); s[2] = f2bf(f0.z); s[3] = f2bf(f0.w);
            s[4] = f2bf(f1.x); s[5] = f2bf(f1.y); s[6] = f2bf(f1.z); s[7] = f2bf(f1.w);
        } else {
            #pragma unroll
            for (int j = 0; j < 8; ++j) s[j] = 0;
        }
        *(bf16x8*)&Xw[row * XROW + l * 8] = s;
    }
    __syncthreads();

    // ---- P1V: cost MFMA -> ces, then V = X.Wv in place (waves 0..6) ----
    if (wv < 7) {
        // preload this wave's 8 A-fragments (all X reads happen here)
        bf16x8 Arow[8];
        const short* xrow = &Xw[(wv * 16 + m16) * XROW + quad * 8];
        #pragma unroll
        for (int kc = 0; kc < 8; ++kc)
            Arow[kc] = *(const bf16x8*)(xrow + kc * 32);

        // cost
        floatx4 accc = (floatx4){0.f, 0.f, 0.f, 0.f};
        const short* bq = Bq + lane * 8;
        #pragma unroll
        for (int kc = 0; kc < 8; ++kc)
            accc = __builtin_amdgcn_mfma_f32_16x16x32_bf16(
                       Arow[kc], *(const bf16x8*)(bq + kc * 512), accc, 0, 0, 0);
        #pragma unroll
        for (int r = 0; r < 4; ++r) {
            int p = wv * 16 + quad * 4 + r;
            int ky = p / 34, jloc = p - ky * 34;
            int ii = i0 + ky, jj = jbase + jloc;
            bool valid = (ky < 3) && (jloc < 33) &&
                         ((unsigned)ii < 64u) && ((unsigned)jj < 64u);
            ces[p * CESROW + m16] = valid ? expf(accc[r]) : 0.f;
        }

        // V projection: 16 n-tiles (pairs), in-place overwrite of own rows
        const short* bv = Wvh + lane * 8;
        #pragma unroll
        for (int ntp = 0; ntp < 8; ++ntp) {
            floatx4 a0 = (floatx4){0.f, 0.f, 0.f, 0.f};
            floatx4 a1 = (floatx4){0.f, 0.f, 0.f, 0.f};
            const short* bp0 = bv + (2 * ntp) * 4096;
            #pragma unroll
            for (int kc = 0; kc < 8; ++kc) {
                bf16x8 b0 = *(const bf16x8*)(bp0 + kc * 512);
                bf16x8 b1 = *(const bf16x8*)(bp0 + 4096 + kc * 512);
                a0 = __builtin_amdgcn_mfma_f32_16x16x32_bf16(Arow[kc], b0, a0, 0, 0, 0);
                a1 = __builtin_amdgcn_mfma_f32_16x16x32_bf16(Arow[kc], b1, a1, 0, 0, 0);
            }
            #pragma unroll
            for (int r = 0; r < 4; ++r) {
                Xw[(wv * 16 + quad * 4 + r) * XROW + ntp * 32 + m16]      = f2bf(a0[r]);
                Xw[(wv * 16 + quad * 4 + r) * XROW + ntp * 32 + 16 + m16] = f2bf(a1[r]);
            }
        }
    }
    __syncthreads();

    // ---- P2a: invden ----
    if (tid < 256) {
        int op = tid >> 4, g = tid & 15;
        float den = 0.f;
        #pragma unroll
        for (int w = 0; w < 9; ++w) {
            int ky = w / 3, kx = w - ky * 3;
            int row = ky * 34 + 2 * op + kx;
            den = fmaf(rpe_exp[w * 16 + g], ces[row * CESROW + g], den);
        }
        invden[op][g] = 1.0f / den;
    }
    __syncthreads();

    // ---- P2b: wcoefs[h][w][op]  (queries q=0/1 merged) ----
    for (int it = tid; it < 1152; it += 512) {
        int op = it / 72, r = it - op * 72;
        int w = r >> 3, h = r & 7;
        int ky = w / 3, kx = w - ky * 3;
        int row = ky * 34 + 2 * op + kx;
        wcoefs[h][w][op] =
            ces[row * CESROW + h]     * rpe_scale[w * 16 + h]     * invden[op][h] +
            ces[row * CESROW + 8 + h] * rpe_scale[w * 16 + 8 + h] * invden[op][8 + h];
    }
    __syncthreads();   // ces dead from here -> pool becomes out_tr

    // ---- P3: stencil on V -> out_tr (thread = (op, 8-feature chunk)) ----
    {
        int op = tid >> 5;                 // 0..15
        int nc = tid & 31;                 // 8-feature chunk
        int n0 = nc * 8;
        int h  = nc >> 2;                  // = n0 >> 5
        float wcv[9];
        #pragma unroll
        for (int w = 0; w < 9; ++w) wcv[w] = wcoefs[h][w][op];

        float o[8];
        #pragma unroll
        for (int j = 0; j < 8; ++j) o[j] = 0.f;
        #pragma unroll
        for (int w = 0; w < 9; ++w) {
            int ky = w / 3, kx = w - ky * 3;
            int row = ky * 34 + 2 * op + kx;
            bf16x8 vv = *(const bf16x8*)&Xw[row * XROW + n0];
            #pragma unroll
            for (int j = 0; j < 8; ++j)
                o[j] = fmaf(wcv[w], bf2f(vv[j]), o[j]);
        }
        bf16x8 ob;
        #pragma unroll
        for (int j = 0; j < 8; ++j) ob[j] = f2bf(o[j]);
        *(bf16x8*)&out_tr[op * XROW + n0] = ob;
    }
    __syncthreads();

    // ---- P5: out = out_tr . Wo (nt pair = wave), write fp32 ----
    {
        floatx4 acc0 = (floatx4){0.f, 0.f, 0.f, 0.f};
        floatx4 acc1 = (floatx4){0.f, 0.f, 0.f, 0.f};
        int nt0 = wv * 2;
        const short* bp = Bo + nt0 * 4096 + lane * 8;
        #pragma unroll
        for (int kc = 0; kc < 8; ++kc) {
            bf16x8 a  = *(const bf16x8*)&out_tr[m16 * XROW + kc * 32 + quad * 8];
            bf16x8 b0 = *(const bf16x8*)(bp + kc * 512);
            bf16x8 b1 = *(const bf16x8*)(bp + 4096 + kc * 512);
            acc0 = __builtin_amdgcn_mfma_f32_16x16x32_bf16(a, b0, acc0, 0, 0, 0);
            acc1 = __builtin_amdgcn_mfma_f32_16x16x32_bf16(a, b1, acc1, 0, 0, 0);
        }
        size_t op0 = (size_t)blk * 16;
        #pragma unroll
        for (int r = 0; r < 4; ++r) {
            out[(op0 + quad * 4 + r) * 256 + nt0 * 16 + m16]       = acc0[r];
            out[(op0 + quad * 4 + r) * 256 + (nt0 + 1) * 16 + m16] = acc1[r];
        }
    }
}

// ---------------------------------------------------------------------------
extern "C" void kernel_launch(void* const* d_in, const int* in_sizes, int n_in,
                              void* d_out, int out_size, void* d_ws, size_t ws_size,
                              hipStream_t stream)
{
    const float* x     = (const float*)d_in[0];
    const float* query = (const float*)d_in[1];
    const float* Wk    = (const float*)d_in[2];
    const float* Wv    = (const float*)d_in[3];
    const float* rpe   = (const float*)d_in[4];
    const float* asw   = (const float*)d_in[5];
    const float* Wo    = (const float*)d_in[6];
    float* out = (float*)d_out;

    float* ws        = (float*)d_ws;
    float* rpe_exp   = ws;                         // 144 f
    float* rpe_scale = ws + 144;                   // 144 f
    short* Bq        = (short*)(ws + 288);         // 4096 bf16
    short* Wvh       = (short*)(ws + 288 + 2048);  // 65536 bf16
    short* Bo        = (short*)(ws + 288 + 2048 + 32768);  // 65536 bf16

    prep_kernel<<<dim3(16), dim3(256), 0, stream>>>(query, Wk, rpe, asw, Wv, Wo,
                                                    rpe_exp, rpe_scale, Bq, Wvh, Bo);
    fused_kernel<<<dim3(2048), dim3(512), 0, stream>>>(x, rpe_exp, rpe_scale,
                                                       Bq, Wvh, Bo, out);
}

// Round 5
// 257.408 us; speedup vs baseline: 1.1910x; 1.1910x over previous
//
#include <hip/hip_runtime.h>
#include <math.h>

typedef __attribute__((ext_vector_type(8))) short bf16x8;   // 8 bf16 = 4 VGPRs
typedef __attribute__((ext_vector_type(4))) float floatx4;

static __device__ __forceinline__ short f2bf(float f) {
    union { float f; unsigned u; } a; a.f = f;
    unsigned r = a.u + 0x7fffu + ((a.u >> 16) & 1u);   // RNE
    return (short)(r >> 16);
}
static __device__ __forceinline__ float bf2f(short s) {
    union { unsigned u; float f; } c; c.u = ((unsigned)(unsigned short)s) << 16;
    return c.f;
}

// ---------------------------------------------------------------------------
// prep: 16 blocks; block bb:
//   - computes qwk rows [bb*16, bb*16+16) and packs them straight into Bq
//   - packs Wv / Wo rows [bb*16, bb*16+16) into Wvh / Bo (coalesced reads)
// ---------------------------------------------------------------------------
__global__ __launch_bounds__(256) void prep_kernel(
    const float* __restrict__ query,        // [2][256]
    const float* __restrict__ Wk,           // [256][256]
    const float* __restrict__ rpe_bias,     // [9][16]
    const float* __restrict__ attn_scale_w, // [9][16]
    const float* __restrict__ Wv,           // [256][256]
    const float* __restrict__ Wo,           // [256][256]
    float* __restrict__ rpe_exp,            // out [9][16]
    float* __restrict__ rpe_scale,          // out [9][16]
    short* __restrict__ Bq,                 // out [4096]  (MFMA b-frag layout)
    short* __restrict__ Wvh,                // out [65536] (full b-frag pack)
    short* __restrict__ Bo)                 // out [65536]
{
    __shared__ float qn[16 * 33];
    __shared__ float Wt[16][260];
    __shared__ float qwk_s[16][17];
    int tid = threadIdx.x, bb = blockIdx.x;

    for (int i = tid; i < 512; i += 256) {
        int qq  = i >> 8;
        int rem = i & 255;
        int h   = rem >> 5;
        int d   = rem & 31;
        qn[((qq << 3) + h) * 33 + d] = query[i];
    }
    for (int i = tid; i < 16 * 256; i += 256)
        Wt[i >> 8][i & 255] = Wk[bb * 16 * 256 + i];
    __syncthreads();
    if (tid < 16) {
        float s = 0.f;
        #pragma unroll
        for (int d = 0; d < 32; ++d) { float t = qn[tid * 33 + d]; s += t * t; }
        float inv = 1.0f / ((sqrtf(s) + 1e-6f) * sqrtf(32.0f));
        #pragma unroll
        for (int d = 0; d < 32; ++d) qn[tid * 33 + d] *= inv;
    }
    __syncthreads();

    int g  = tid & 15;
    int Dl = tid >> 4;
    int h2 = g & 7;
    float acc = 0.f;
    #pragma unroll
    for (int d = 0; d < 32; ++d)
        acc += qn[g * 33 + d] * Wt[Dl][h2 * 32 + d];
    qwk_s[Dl][g] = acc;
    __syncthreads();

    // Bq pack for this block's 16 k-rows (b-frag: id = kc*512 + lane*8 + j)
    {
        int kl = tid >> 4, gg = tid & 15;
        int k  = bb * 16 + kl;
        int kc = k >> 5, q5 = k & 31, qd = q5 >> 3, j = q5 & 7;
        int lane = qd * 16 + gg;
        Bq[kc * 512 + lane * 8 + j] = f2bf(qwk_s[kl][gg]);
    }

    // Wvh / Bo pack: coalesced row reads (thread = column n)
    for (int kl = 0; kl < 16; ++kl) {
        int k  = bb * 16 + kl;
        int kc = k >> 5, q5 = k & 31, qd = q5 >> 3, j = q5 & 7;
        int n  = tid;
        int gg = n & 15;
        int lane = qd * 16 + gg;
        float vv = Wv[k * 256 + n];
        float vo = Wo[k * 256 + n];
        int nt  = n >> 4;
        Wvh[nt * 4096 + kc * 512 + lane * 8 + j] = f2bf(vv);
        Bo[nt * 4096 + kc * 512 + lane * 8 + j]  = f2bf(vo);
    }

    if (bb == 0 && tid < 144) {
        float r = expf(rpe_bias[tid]);
        rpe_exp[tid]   = r;
        rpe_scale[tid] = r * attn_scale_w[tid];
    }
}

// ---------------------------------------------------------------------------
// fused mega-kernel: block = 16 output pixels (half an output row), 512 thr.
// V-formulation, B-STATIONARY projection (fixes round-4's 7x Wvh L2 stream):
// P0:  stage x window (112 rows x 256 ch) -> bf16 LDS (Xw)
// Bv:  wave wv preloads b-frags for its nt-pair (2wv,2wv+1) ONCE (64 VGPR)
// P1:  cost MFMA -> ces (waves 0..6; A-frags from LDS)
// P1V: for m = 0..6: all waves read m-tile m A-frags from Xw, MFMA against
//      resident Bv; __syncthreads(); write V[m] in place over Xw rows
//      [16m,16m+16) (all waves have consumed those rows). Iter m+1 reads
//      disjoint rows -> single barrier per m suffices.
// P2a/P2b: invden; wcoefs[h][w][op]
// P3:  stencil: pre[op][n] = sum_w wc[op][w][n>>5] * V[row(op,w)][n]
// P5:  out = out_tr . Wo   (out_tr aliases ces pool, dead after P2b)
// ---------------------------------------------------------------------------
#define XROW 264
#define CESROW 19
__global__ __launch_bounds__(512) void fused_kernel(
    const float* __restrict__ x,          // [131072][256] fp32
    const float* __restrict__ rpe_exp,    // [9][16]
    const float* __restrict__ rpe_scale,  // [9][16]
    const short* __restrict__ Bq,         // [4096]
    const short* __restrict__ Wvh,        // [65536]
    const short* __restrict__ Bo,         // [65536]
    float* __restrict__ out)              // [32768][256] fp32
{
    __shared__ short Xw[112 * XROW];                        // 59136 B (X, then V)
    __shared__ __align__(16) unsigned char pool[112 * CESROW * 4]; // 8512 B
    __shared__ float wcoefs[8][9][16];                      // 4608 B [h][w][op]
    __shared__ float invden[16][16];                        // 1024 B (tot 73280)

    float* ces    = (float*)pool;     // live P1..P2b
    short* out_tr = (short*)pool;     // live P3..P5 (16 rows x XROW)

    int tid  = threadIdx.x;
    int lane = tid & 63, wv = tid >> 6;
    int m16  = lane & 15, quad = lane >> 4;

    int blk0 = blockIdx.x;
    int blk  = ((blk0 & 7) << 8) | (blk0 >> 3);  // XCD-contiguous, bijective
    int b   = blk >> 6;
    int io  = (blk >> 1) & 31;
    int hf  = blk & 1;
    int i0  = io * 2 - 1;
    int jbase = hf * 32 - 1;

    // ---- P0: stage window, coalesced, zero-fill OOB/pad ----
    #pragma unroll
    for (int i = 0; i < 7; ++i) {
        int it  = tid + i * 512;          // 0..3583 = 112 rows x 32 chunks
        int row = it >> 5;
        int l   = it & 31;
        int ky  = row / 34;
        int jloc = row - ky * 34;
        int ii = i0 + ky, jj = jbase + jloc;
        bool valid = (ky < 3) && (jloc < 33) &&
                     ((unsigned)ii < 64u) && ((unsigned)jj < 64u);
        bf16x8 s;
        if (valid) {
            const float* xp = x + ((size_t)(((b << 6) + ii) << 6) + jj) * 256 + l * 8;
            float4 f0 = *(const float4*)xp;
            float4 f1 = *(const float4*)(xp + 4);
            s[0] = f2bf(f0.x); s[1] = f2bf(f0.y); s[2] = f2bf(f0.z); s[3] = f2bf(f0.w);
            s[4] = f2bf(f1.x); s[5] = f2bf(f1.y); s[6] = f2bf(f1.z); s[7] = f2bf(f1.w);
        } else {
            #pragma unroll
            for (int j = 0; j < 8; ++j) s[j] = 0;
        }
        *(bf16x8*)&Xw[row * XROW + l * 8] = s;
    }
    __syncthreads();

    // ---- Bv preload: wave wv's nt pair, resident for whole P1V ----
    bf16x8 Bv0[8], Bv1[8];
    {
        const short* bv = Wvh + (2 * wv) * 4096 + lane * 8;
        #pragma unroll
        for (int kc = 0; kc < 8; ++kc) {
            Bv0[kc] = *(const bf16x8*)(bv + kc * 512);
            Bv1[kc] = *(const bf16x8*)(bv + 4096 + kc * 512);
        }
    }

    // ---- P1: cost MFMA -> ces (waves 0..6, A-frags from LDS) ----
    if (wv < 7) {
        floatx4 accc = (floatx4){0.f, 0.f, 0.f, 0.f};
        const short* bq   = Bq + lane * 8;
        const short* xrow = &Xw[(wv * 16 + m16) * XROW + quad * 8];
        #pragma unroll
        for (int kc = 0; kc < 8; ++kc) {
            bf16x8 a = *(const bf16x8*)(xrow + kc * 32);
            accc = __builtin_amdgcn_mfma_f32_16x16x32_bf16(
                       a, *(const bf16x8*)(bq + kc * 512), accc, 0, 0, 0);
        }
        #pragma unroll
        for (int r = 0; r < 4; ++r) {
            int p = wv * 16 + quad * 4 + r;
            int ky = p / 34, jloc = p - ky * 34;
            int ii = i0 + ky, jj = jbase + jloc;
            bool valid = (ky < 3) && (jloc < 33) &&
                         ((unsigned)ii < 64u) && ((unsigned)jj < 64u);
            ces[p * CESROW + m16] = valid ? expf(accc[r]) : 0.f;
        }
    }

    // ---- P1V: B-stationary V = X.Wv, in place, barrier per m-tile ----
    for (int m = 0; m < 7; ++m) {
        floatx4 a0 = (floatx4){0.f, 0.f, 0.f, 0.f};
        floatx4 a1 = (floatx4){0.f, 0.f, 0.f, 0.f};
        const short* xrow = &Xw[(m * 16 + m16) * XROW + quad * 8];
        #pragma unroll
        for (int kc = 0; kc < 8; ++kc) {
            bf16x8 af = *(const bf16x8*)(xrow + kc * 32);
            a0 = __builtin_amdgcn_mfma_f32_16x16x32_bf16(af, Bv0[kc], a0, 0, 0, 0);
            a1 = __builtin_amdgcn_mfma_f32_16x16x32_bf16(af, Bv1[kc], a1, 0, 0, 0);
        }
        __syncthreads();   // all waves' reads of m-tile m complete
        #pragma unroll
        for (int r = 0; r < 4; ++r) {
            Xw[(m * 16 + quad * 4 + r) * XROW + wv * 32 + m16]      = f2bf(a0[r]);
            Xw[(m * 16 + quad * 4 + r) * XROW + wv * 32 + 16 + m16] = f2bf(a1[r]);
        }
    }

    // ---- P2a: invden (reads ces; no Xw hazard with trailing V writes) ----
    __syncthreads();
    if (tid < 256) {
        int op = tid >> 4, g = tid & 15;
        float den = 0.f;
        #pragma unroll
        for (int w = 0; w < 9; ++w) {
            int ky = w / 3, kx = w - ky * 3;
            int row = ky * 34 + 2 * op + kx;
            den = fmaf(rpe_exp[w * 16 + g], ces[row * CESROW + g], den);
        }
        invden[op][g] = 1.0f / den;
    }
    __syncthreads();

    // ---- P2b: wcoefs[h][w][op]  (queries q=0/1 merged) ----
    for (int it = tid; it < 1152; it += 512) {
        int op = it / 72, r = it - op * 72;
        int w = r >> 3, h = r & 7;
        int ky = w / 3, kx = w - ky * 3;
        int row = ky * 34 + 2 * op + kx;
        wcoefs[h][w][op] =
            ces[row * CESROW + h]     * rpe_scale[w * 16 + h]     * invden[op][h] +
            ces[row * CESROW + 8 + h] * rpe_scale[w * 16 + 8 + h] * invden[op][8 + h];
    }
    __syncthreads();   // ces dead from here -> pool becomes out_tr

    // ---- P3: stencil on V -> out_tr (thread = (op, 8-feature chunk)) ----
    {
        int op = tid >> 5;                 // 0..15
        int nc = tid & 31;                 // 8-feature chunk
        int n0 = nc * 8;
        int h  = nc >> 2;                  // = n0 >> 5
        float wcv[9];
        #pragma unroll
        for (int w = 0; w < 9; ++w) wcv[w] = wcoefs[h][w][op];

        float o[8];
        #pragma unroll
        for (int j = 0; j < 8; ++j) o[j] = 0.f;
        #pragma unroll
        for (int w = 0; w < 9; ++w) {
            int ky = w / 3, kx = w - ky * 3;
            int row = ky * 34 + 2 * op + kx;
            bf16x8 vv = *(const bf16x8*)&Xw[row * XROW + n0];
            #pragma unroll
            for (int j = 0; j < 8; ++j)
                o[j] = fmaf(wcv[w], bf2f(vv[j]), o[j]);
        }
        bf16x8 ob;
        #pragma unroll
        for (int j = 0; j < 8; ++j) ob[j] = f2bf(o[j]);
        *(bf16x8*)&out_tr[op * XROW + n0] = ob;
    }
    __syncthreads();

    // ---- P5: out = out_tr . Wo (nt pair = wave), write fp32 ----
    {
        floatx4 acc0 = (floatx4){0.f, 0.f, 0.f, 0.f};
        floatx4 acc1 = (floatx4){0.f, 0.f, 0.f, 0.f};
        int nt0 = wv * 2;
        const short* bp = Bo + nt0 * 4096 + lane * 8;
        #pragma unroll
        for (int kc = 0; kc < 8; ++kc) {
            bf16x8 a  = *(const bf16x8*)&out_tr[m16 * XROW + kc * 32 + quad * 8];
            bf16x8 b0 = *(const bf16x8*)(bp + kc * 512);
            bf16x8 b1 = *(const bf16x8*)(bp + 4096 + kc * 512);
            acc0 = __builtin_amdgcn_mfma_f32_16x16x32_bf16(a, b0, acc0, 0, 0, 0);
            acc1 = __builtin_amdgcn_mfma_f32_16x16x32_bf16(a, b1, acc1, 0, 0, 0);
        }
        size_t op0 = (size_t)blk * 16;
        #pragma unroll
        for (int r = 0; r < 4; ++r) {
            out[(op0 + quad * 4 + r) * 256 + nt0 * 16 + m16]       = acc0[r];
            out[(op0 + quad * 4 + r) * 256 + (nt0 + 1) * 16 + m16] = acc1[r];
        }
    }
}

// ---------------------------------------------------------------------------
extern "C" void kernel_launch(void* const* d_in, const int* in_sizes, int n_in,
                              void* d_out, int out_size, void* d_ws, size_t ws_size,
                              hipStream_t stream)
{
    const float* x     = (const float*)d_in[0];
    const float* query = (const float*)d_in[1];
    const float* Wk    = (const float*)d_in[2];
    const float* Wv    = (const float*)d_in[3];
    const float* rpe   = (const float*)d_in[4];
    const float* asw   = (const float*)d_in[5];
    const float* Wo    = (const float*)d_in[6];
    float* out = (float*)d_out;

    float* ws        = (float*)d_ws;
    float* rpe_exp   = ws;                         // 144 f
    float* rpe_scale = ws + 144;                   // 144 f
    short* Bq        = (short*)(ws + 288);         // 4096 bf16
    short* Wvh       = (short*)(ws + 288 + 2048);  // 65536 bf16
    short* Bo        = (short*)(ws + 288 + 2048 + 32768);  // 65536 bf16

    prep_kernel<<<dim3(16), dim3(256), 0, stream>>>(query, Wk, rpe, asw, Wv, Wo,
                                                    rpe_exp, rpe_scale, Bq, Wvh, Bo);
    fused_kernel<<<dim3(2048), dim3(512), 0, stream>>>(x, rpe_exp, rpe_scale,
                                                       Bq, Wvh, Bo, out);
}